// Round 10
// baseline (198.232 us; speedup 1.0000x reference)
//
#include <hip/hip_runtime.h>
#include <hip/hip_cooperative_groups.h>

// TT Q-gather v11 — ONE cooperative dispatch: build + grid.sync + gather.
//
// R9 post-mortem: v4/v8/v10 all ~90.0 total; kernel content (chain form,
// staging count, elems/thread) is irrelevant. Pipe models put both kernels
// at ~10us; the non-fill residual is ~48us -> the cost lives BETWEEN
// kernels (2nd dispatch, build launch, graph gaps, DVFS ramp of small
// core-bound kernels after the memory-bound fill). v11 collapses to a
// single cooperative kernel:
//   phase 1: build V01/U67 into ws (stride loop, 1 entry/thread, same
//            arithmetic as build_tables) + per-block G2..G5 -> LDS bf16
//            conversion (reads L2-hot inputs; Gt ws image deleted).
//   grid.sync()
//   phase 2: v10 gather verbatim (2 elems/thread, pipelined chain).
// If total stays ~90, floor = fill(42) + fixed graph machinery -> declare.
//
// ws layout (ushort units):
//   V01 @ 0       : [s0][s1][s] 256*256*8   (1 MB)
//   U67 @ 524288  : [s6][a7][r] 256*256*8   (1 MB)

namespace cg = cooperative_groups;

#define NN 256
#define RR 8
#define NR 2048   // N * R
#define U67_OFF 524288
#define GT_CORE 16384   // ushorts per core in LDS (32 KB)

__device__ __forceinline__ unsigned short f2bf_rne(float f) {
    unsigned int u = __float_as_uint(f);
    u += 0x7FFFu + ((u >> 16) & 1u);
    return (unsigned short)(u >> 16);
}

__device__ __forceinline__ uint4 pack8bf(const float* a) {
    return make_uint4(
        f2bf_rne(a[0]) | ((unsigned int)f2bf_rne(a[1]) << 16),
        f2bf_rne(a[2]) | ((unsigned int)f2bf_rne(a[3]) << 16),
        f2bf_rne(a[4]) | ((unsigned int)f2bf_rne(a[5]) << 16),
        f2bf_rne(a[6]) | ((unsigned int)f2bf_rne(a[7]) << 16));
}

#define BF2F_LO(u) __uint_as_float((u) << 16)
#define BF2F_HI(u) __uint_as_float((u) & 0xFFFF0000u)

// stage one core from global fp32 into LDS (bf16), 512 thr x 4 (r,n)-pairs
#define STAGE_CORE(k, Gk)                                                   \
    do {                                                                    \
        _Pragma("unroll") for (int i = 0; i < 4; ++i) {                     \
            const int p = (i << 9) + t;       /* 0..2047 */                 \
            const int r = p >> 8, n = p & 255;                              \
            const float4* sp = (const float4*)((Gk) + r * NR + n * RR);     \
            float4 x = sp[0], y = sp[1];                                    \
            float a8[8] = {x.x, x.y, x.z, x.w, y.x, y.y, y.z, y.w};         \
            ((uint4*)lut)[(k) * 2048 + r * 256 + n] = pack8bf(a8);          \
        }                                                                   \
    } while (0)

// load row-pair (r=2rp, 2rp+1) of core k, column-slice n into q0,q1
#define LP(q0, q1, k, nk, rp)                                               \
    do {                                                                    \
        const uint4* _p = l4 + (k) * 2048 + (nk) + (rp) * 512;              \
        q0 = _p[0];                                                         \
        q1 = _p[256];                                                       \
    } while (0)

// accumulate row-pair rp with weights v[2rp], v[2rp+1] into acc[0..7]
#define FP(q0, q1, rp)                                                      \
    do {                                                                    \
        const float wa = v[2 * (rp)], wb = v[2 * (rp) + 1];                 \
        acc[0] += wa * BF2F_LO(q0.x); acc[0] += wb * BF2F_LO(q1.x);         \
        acc[1] += wa * BF2F_HI(q0.x); acc[1] += wb * BF2F_HI(q1.x);         \
        acc[2] += wa * BF2F_LO(q0.y); acc[2] += wb * BF2F_LO(q1.y);         \
        acc[3] += wa * BF2F_HI(q0.y); acc[3] += wb * BF2F_HI(q1.y);         \
        acc[4] += wa * BF2F_LO(q0.z); acc[4] += wb * BF2F_LO(q1.z);         \
        acc[5] += wa * BF2F_HI(q0.z); acc[5] += wb * BF2F_HI(q1.z);         \
        acc[6] += wa * BF2F_LO(q0.w); acc[6] += wb * BF2F_LO(q1.w);         \
        acc[7] += wa * BF2F_HI(q0.w); acc[7] += wb * BF2F_HI(q1.w);         \
    } while (0)

#define ENDST                                                               \
    do {                                                                    \
        _Pragma("unroll") for (int i = 0; i < 8; ++i) {                     \
            v[i] = acc[i]; acc[i] = 0.f;                                    \
        }                                                                   \
    } while (0)

// full per-element chain (v10 verbatim)
#define CHAIN_FULL(uvx, uex, c2, c3, c4, c5, bx, actx)                      \
    do {                                                                    \
        float v[8], acc[8];                                                 \
        v[0] = BF2F_LO(uvx.x); v[1] = BF2F_HI(uvx.x);                       \
        v[2] = BF2F_LO(uvx.y); v[3] = BF2F_HI(uvx.y);                       \
        v[4] = BF2F_LO(uvx.z); v[5] = BF2F_HI(uvx.z);                       \
        v[6] = BF2F_LO(uvx.w); v[7] = BF2F_HI(uvx.w);                       \
        _Pragma("unroll") for (int i = 0; i < 8; ++i) acc[i] = 0.f;         \
        uint4 X0, X1, Y0, Y1, Z0, Z1;                                       \
        LP(X0, X1, 0, c2, 0);                                               \
        LP(Y0, Y1, 0, c2, 1);                                               \
        LP(Z0, Z1, 0, c2, 2);  FP(X0, X1, 0);                               \
        LP(X0, X1, 0, c2, 3);  FP(Y0, Y1, 1);                               \
        LP(Y0, Y1, 1, c3, 0);  FP(Z0, Z1, 2);                               \
        LP(Z0, Z1, 1, c3, 1);  FP(X0, X1, 3);  ENDST;                       \
        LP(X0, X1, 1, c3, 2);  FP(Y0, Y1, 0);                               \
        LP(Y0, Y1, 1, c3, 3);  FP(Z0, Z1, 1);                               \
        LP(Z0, Z1, 2, c4, 0);  FP(X0, X1, 2);                               \
        LP(X0, X1, 2, c4, 1);  FP(Y0, Y1, 3);  ENDST;                       \
        LP(Y0, Y1, 2, c4, 2);  FP(Z0, Z1, 0);                               \
        LP(Z0, Z1, 2, c4, 3);  FP(X0, X1, 1);                               \
        LP(X0, X1, 3, c5, 0);  FP(Y0, Y1, 2);                               \
        LP(Y0, Y1, 3, c5, 1);  FP(Z0, Z1, 3);  ENDST;                       \
        LP(Z0, Z1, 3, c5, 2);  FP(X0, X1, 0);                               \
        LP(X0, X1, 3, c5, 3);  FP(Y0, Y1, 1);                               \
                               FP(Z0, Z1, 2);                               \
                               FP(X0, X1, 3);  ENDST;                       \
        float q = v[0] * BF2F_LO(uex.x) + v[1] * BF2F_HI(uex.x)             \
                + v[2] * BF2F_LO(uex.y) + v[3] * BF2F_HI(uex.y)             \
                + v[4] * BF2F_LO(uex.z) + v[5] * BF2F_HI(uex.z)             \
                + v[6] * BF2F_LO(uex.w) + v[7] * BF2F_HI(uex.w);            \
        if (actx) out[bx] = q;                                              \
    } while (0)

__global__ __launch_bounds__(512, 2) void tt_fused(
    const float* __restrict__ G0, const float* __restrict__ G1,
    const float* __restrict__ G6, const float* __restrict__ G7,
    const float* __restrict__ G2, const float* __restrict__ G3,
    const float* __restrict__ G4, const float* __restrict__ G5,
    const int* __restrict__ states, const int* __restrict__ actions,
    unsigned short* __restrict__ wsb, float* __restrict__ out, int B) {
    __shared__ unsigned short lut[4 * GT_CORE];   // 128 KB

    const int t = threadIdx.x;
    const int gtid = blockIdx.x * 512 + t;
    const int gstride = gridDim.x * 512;

    // ---- phase 1a: per-block LDS image of G2..G5 (fp32 -> bf16) ----
    STAGE_CORE(0, G2);
    STAGE_CORE(1, G3);
    STAGE_CORE(2, G4);
    STAGE_CORE(3, G5);

    // ---- phase 1b: indices for phase 2 (inputs; safe before sync) ----
    const int bA = blockIdx.x * 1024 + t;          // element A
    const int bB = bA + 512;                       // element B
    const bool actA = (bA < B), actB = (bB < B);
    const int baseA = actA ? bA * 7 : 0;
    const int baseB = actB ? bB * 7 : 0;
    const int a0 = states[baseA + 0] & 255, e0 = states[baseB + 0] & 255;
    const int a1 = states[baseA + 1] & 255, e1 = states[baseB + 1] & 255;
    const int a2 = states[baseA + 2] & 255, e2 = states[baseB + 2] & 255;
    const int a3 = states[baseA + 3] & 255, e3 = states[baseB + 3] & 255;
    const int a4 = states[baseA + 4] & 255, e4 = states[baseB + 4] & 255;
    const int a5 = states[baseA + 5] & 255, e5 = states[baseB + 5] & 255;
    const int a6 = states[baseA + 6] & 255, e6 = states[baseB + 6] & 255;
    const int aa = actions[actA ? bA : 0] & 255;
    const int ea = actions[actB ? bB : 0] & 255;

    // ---- phase 1c: build V01 / U67 into ws (1 entry per unit) ----
    for (int u = gtid; u < 2 * NN * NN; u += gstride) {
        if (u < NN * NN) {
            // V01[n0][n1][s] = sum_r G0[n0,r] * G1[r,n1,s]
            const int n0 = u >> 8, n1 = u & 255;
            float acc[RR] = {0.f,0.f,0.f,0.f,0.f,0.f,0.f,0.f};
#pragma unroll
            for (int r = 0; r < RR; ++r) {
                float ar = G0[n0 * RR + r];
                const float4* p = (const float4*)(G1 + r * NR + n1 * RR);
                float4 x = p[0], y = p[1];
                acc[0] += ar * x.x; acc[1] += ar * x.y;
                acc[2] += ar * x.z; acc[3] += ar * x.w;
                acc[4] += ar * y.x; acc[5] += ar * y.y;
                acc[6] += ar * y.z; acc[7] += ar * y.w;
            }
            *(uint4*)(wsb + n0 * 2048 + n1 * 8) = pack8bf(acc);
        } else {
            // U67[n6][n7][r] = sum_s G6[r,n6,s] * G7[s,n7]
            const int w = u - NN * NN;
            const int n6 = w >> 8, n7 = w & 255;
            float g7v[RR];
#pragma unroll
            for (int s = 0; s < RR; ++s) g7v[s] = G7[s * NN + n7];
            float uo[RR];
#pragma unroll
            for (int r = 0; r < RR; ++r) {
                float acc = 0.f;
#pragma unroll
                for (int s = 0; s < RR; ++s)
                    acc += G6[r * NR + n6 * RR + s] * g7v[s];
                uo[r] = acc;
            }
            *(uint4*)(wsb + U67_OFF + n6 * 2048 + n7 * 8) = pack8bf(uo);
        }
    }

    // ---- barriers: LDS (block) + tables (grid, device-scope) ----
    __threadfence();
    cg::this_grid().sync();
    __syncthreads();

    // ---- phase 2: v10 gather body ----
    const uint4 uvA = *(const uint4*)(wsb + a0 * 2048 + a1 * 8);
    const uint4 ueA = *(const uint4*)(wsb + U67_OFF + a6 * 2048 + aa * 8);
    const uint4 uvB = *(const uint4*)(wsb + e0 * 2048 + e1 * 8);
    const uint4 ueB = *(const uint4*)(wsb + U67_OFF + e6 * 2048 + ea * 8);

    const uint4* l4 = (const uint4*)lut;
    CHAIN_FULL(uvA, ueA, a2, a3, a4, a5, bA, actA);
    CHAIN_FULL(uvB, ueB, e2, e3, e4, e5, bB, actB);
}

extern "C" void kernel_launch(void* const* d_in, const int* in_sizes, int n_in,
                              void* d_out, int out_size, void* d_ws, size_t ws_size,
                              hipStream_t stream) {
    const float* G0 = (const float*)d_in[0];
    const float* G1 = (const float*)d_in[1];
    const float* G2 = (const float*)d_in[2];
    const float* G3 = (const float*)d_in[3];
    const float* G4 = (const float*)d_in[4];
    const float* G5 = (const float*)d_in[5];
    const float* G6 = (const float*)d_in[6];
    const float* G7 = (const float*)d_in[7];
    const int* states  = (const int*)d_in[8];
    const int* actions = (const int*)d_in[9];
    float* out = (float*)d_out;
    int B = in_sizes[9];

    unsigned short* wsb = (unsigned short*)d_ws;   // 2 MB used

    int nblk = (B + 1023) / 1024;                  // 256 for B=262144
    void* args[] = {
        (void*)&G0, (void*)&G1, (void*)&G6, (void*)&G7,
        (void*)&G2, (void*)&G3, (void*)&G4, (void*)&G5,
        (void*)&states, (void*)&actions, (void*)&wsb, (void*)&out, (void*)&B};
    hipLaunchCooperativeKernel((const void*)tt_fused, dim3(nblk), dim3(512),
                               args, 0, stream);
}

// Round 11
// 95.382 us; speedup vs baseline: 2.0783x; 2.0783x over previous
//
#include <hip/hip_runtime.h>

// TT Q-gather v12 — split chain into two half-kernels at 4 waves/SIMD.
//
//   LO: v = V01[s0][s1] @ G2[:,s2,:] @ G3[:,s3,:]   -> vtmp (fp32, ws)
//   HI: q = (vtmp @ G4[:,s4,:] @ G5[:,s5,:]) . U67[s6][a7]
//
// R10 post-mortem: coop grid.sync = +65us, dead. Ledger: two-kernel
// gather pinned at ~33us (90.4 - fill 42 - build+gaps 15), model says
// 6-8us. Every non-spilled variant ran 128KB LDS = 1 block/CU = 2
// waves/SIMD with depth-2 prefetch -> unhidden LDS latency is the only
// consistent explanation (all >2-wave attempts died by spill or paging).
// v12 gets 4 waves/SIMD legitimately: each half-kernel uses 64 KB LDS
// (2 cores, staged straight from fp32 inputs -- Gt ws image deleted),
// 512 blocks x 512 thr, 2 blocks/CU. vtmp fp32 roundtrip is exact ->
// absmax unchanged. Costs: +1 launch gap, +16 MB L3 traffic.
//
// ws layout (ushort units):
//   V01  @ 0       : [s0][s1][s] 256*256*8   (1 MB)
//   U67  @ 524288  : [s6][a7][r] 256*256*8   (1 MB)
//   vtmp @ 1048576 : [b][8] fp32             (8 MB)

#define NN 256
#define RR 8
#define NR 2048   // N * R
#define U67_OFF 524288
#define VT_OFF  1048576   // ushort units -> byte offset 2 MB

__device__ __forceinline__ unsigned short f2bf_rne(float f) {
    unsigned int u = __float_as_uint(f);
    u += 0x7FFFu + ((u >> 16) & 1u);
    return (unsigned short)(u >> 16);
}

__device__ __forceinline__ uint4 pack8bf(const float* a) {
    return make_uint4(
        f2bf_rne(a[0]) | ((unsigned int)f2bf_rne(a[1]) << 16),
        f2bf_rne(a[2]) | ((unsigned int)f2bf_rne(a[3]) << 16),
        f2bf_rne(a[4]) | ((unsigned int)f2bf_rne(a[5]) << 16),
        f2bf_rne(a[6]) | ((unsigned int)f2bf_rne(a[7]) << 16));
}

// 512 blocks x 256 threads: 0..255 -> V01 row n0, 256..511 -> U67 row n6
__global__ __launch_bounds__(256) void build_tables(
    const float* __restrict__ G0, const float* __restrict__ G1,
    const float* __restrict__ G6, const float* __restrict__ G7,
    unsigned short* __restrict__ wsb) {
    const int t = threadIdx.x;
    const int bid = blockIdx.x;

    if (bid < NN) {
        // V01[n0][n1][s] = sum_r G0[n0,r] * G1[r,n1,s]
        const int n0 = bid, n1 = t;
        float acc[RR] = {0.f,0.f,0.f,0.f,0.f,0.f,0.f,0.f};
#pragma unroll
        for (int r = 0; r < RR; ++r) {
            float ar = G0[n0 * RR + r];
            const float4* p = (const float4*)(G1 + r * NR + n1 * RR);
            float4 x = p[0], y = p[1];
            acc[0] += ar * x.x; acc[1] += ar * x.y;
            acc[2] += ar * x.z; acc[3] += ar * x.w;
            acc[4] += ar * y.x; acc[5] += ar * y.y;
            acc[6] += ar * y.z; acc[7] += ar * y.w;
        }
        *(uint4*)(wsb + n0 * 2048 + n1 * 8) = pack8bf(acc);
    } else {
        // U67[n6][n7][r] = sum_s G6[r,n6,s] * G7[s,n7]
        const int n6 = bid - NN, n7 = t;
        float g7v[RR];
#pragma unroll
        for (int s = 0; s < RR; ++s) g7v[s] = G7[s * NN + n7];
        float u[RR];
#pragma unroll
        for (int r = 0; r < RR; ++r) {
            float acc = 0.f;
#pragma unroll
            for (int s = 0; s < RR; ++s)
                acc += G6[r * NR + n6 * RR + s] * g7v[s];
            u[r] = acc;
        }
        *(uint4*)(wsb + U67_OFF + n6 * 2048 + n7 * 8) = pack8bf(u);
    }
}

#define BF2F_LO(u) __uint_as_float((u) << 16)
#define BF2F_HI(u) __uint_as_float((u) & 0xFFFF0000u)

// stage one core (slot kc of 2) from fp32 global into LDS bf16 [r][n][s]
#define STAGE_CORE(kc, Gk)                                                  \
    do {                                                                    \
        _Pragma("unroll") for (int i = 0; i < 4; ++i) {                     \
            const int p = (i << 9) + t;       /* 0..2047 */                 \
            const int r = p >> 8, n = p & 255;                              \
            const float4* sp = (const float4*)((Gk) + r * NR + n * RR);     \
            float4 x = sp[0], y = sp[1];                                    \
            float a8[8] = {x.x, x.y, x.z, x.w, y.x, y.y, y.z, y.w};         \
            ((uint4*)lut)[(kc) * 2048 + r * 256 + n] = pack8bf(a8);         \
        }                                                                   \
    } while (0)

// load row-pair (r=2rp,2rp+1) of LDS core kc, column-slice n into q0,q1
#define LP(q0, q1, kc, nk, rp)                                              \
    do {                                                                    \
        const uint4* _p = l4 + (kc) * 2048 + (nk) + (rp) * 512;             \
        q0 = _p[0];                                                         \
        q1 = _p[256];                                                       \
    } while (0)

// accumulate row-pair rp with weights v[2rp], v[2rp+1] into acc[0..7]
#define FP(q0, q1, rp)                                                      \
    do {                                                                    \
        const float wa = v[2 * (rp)], wb = v[2 * (rp) + 1];                 \
        acc[0] += wa * BF2F_LO(q0.x); acc[0] += wb * BF2F_LO(q1.x);         \
        acc[1] += wa * BF2F_HI(q0.x); acc[1] += wb * BF2F_HI(q1.x);         \
        acc[2] += wa * BF2F_LO(q0.y); acc[2] += wb * BF2F_LO(q1.y);         \
        acc[3] += wa * BF2F_HI(q0.y); acc[3] += wb * BF2F_HI(q1.y);         \
        acc[4] += wa * BF2F_LO(q0.z); acc[4] += wb * BF2F_LO(q1.z);         \
        acc[5] += wa * BF2F_HI(q0.z); acc[5] += wb * BF2F_HI(q1.z);         \
        acc[6] += wa * BF2F_LO(q0.w); acc[6] += wb * BF2F_LO(q1.w);         \
        acc[7] += wa * BF2F_HI(q0.w); acc[7] += wb * BF2F_HI(q1.w);         \
    } while (0)

#define ENDST                                                               \
    do {                                                                    \
        _Pragma("unroll") for (int i = 0; i < 8; ++i) {                     \
            v[i] = acc[i]; acc[i] = 0.f;                                    \
        }                                                                   \
    } while (0)

// two-stage pipelined chain over LDS cores (0,c0) then (1,c1)
#define CHAIN2(c0, c1)                                                      \
    do {                                                                    \
        uint4 X0, X1, Y0, Y1, Z0, Z1;                                       \
        LP(X0, X1, 0, c0, 0);                                               \
        LP(Y0, Y1, 0, c0, 1);                                               \
        LP(Z0, Z1, 0, c0, 2);  FP(X0, X1, 0);                               \
        LP(X0, X1, 0, c0, 3);  FP(Y0, Y1, 1);                               \
        LP(Y0, Y1, 1, c1, 0);  FP(Z0, Z1, 2);                               \
        LP(Z0, Z1, 1, c1, 1);  FP(X0, X1, 3);  ENDST;                       \
        LP(X0, X1, 1, c1, 2);  FP(Y0, Y1, 0);                               \
        LP(Y0, Y1, 1, c1, 3);  FP(Z0, Z1, 1);                               \
                               FP(X0, X1, 2);                               \
                               FP(Y0, Y1, 3);  ENDST;                       \
    } while (0)

__global__ __launch_bounds__(512, 2) void tt_lo(
    const unsigned short* __restrict__ wsb,
    const float* __restrict__ G2, const float* __restrict__ G3,
    const int* __restrict__ states, float* __restrict__ vtmp, int B) {
    __shared__ unsigned short lut[2 * 16384];   // 64 KB: G2, G3

    const int t = threadIdx.x;
    const int b = blockIdx.x * 512 + t;
    const bool active = (b < B);
    const int base = active ? b * 7 : 0;
    const int s0 = states[base + 0] & 255;
    const int s1 = states[base + 1] & 255;
    const int s2 = states[base + 2] & 255;
    const int s3 = states[base + 3] & 255;

    const uint4 uv = *(const uint4*)(wsb + s0 * 2048 + s1 * 8);

    STAGE_CORE(0, G2);
    STAGE_CORE(1, G3);
    __syncthreads();

    float v[8], acc[8];
    v[0] = BF2F_LO(uv.x); v[1] = BF2F_HI(uv.x);
    v[2] = BF2F_LO(uv.y); v[3] = BF2F_HI(uv.y);
    v[4] = BF2F_LO(uv.z); v[5] = BF2F_HI(uv.z);
    v[6] = BF2F_LO(uv.w); v[7] = BF2F_HI(uv.w);
#pragma unroll
    for (int i = 0; i < 8; ++i) acc[i] = 0.f;

    const uint4* l4 = (const uint4*)lut;
    CHAIN2(s2, s3);

    if (active) {
        float4* vo = (float4*)(vtmp + b * 8);
        vo[0] = make_float4(v[0], v[1], v[2], v[3]);
        vo[1] = make_float4(v[4], v[5], v[6], v[7]);
    }
}

__global__ __launch_bounds__(512, 2) void tt_hi(
    const unsigned short* __restrict__ wsb,
    const float* __restrict__ G4, const float* __restrict__ G5,
    const int* __restrict__ states, const int* __restrict__ actions,
    const float* __restrict__ vtmp, float* __restrict__ out, int B) {
    __shared__ unsigned short lut[2 * 16384];   // 64 KB: G4, G5

    const int t = threadIdx.x;
    const int b = blockIdx.x * 512 + t;
    const bool active = (b < B);
    const int base = active ? b * 7 : 0;
    const int s4 = states[base + 4] & 255;
    const int s5 = states[base + 5] & 255;
    const int s6 = states[base + 6] & 255;
    const int a7 = actions[active ? b : 0] & 255;

    const float4* vi = (const float4*)(vtmp + (active ? b : 0) * 8);
    const float4 va = vi[0], vb = vi[1];
    const uint4 ue = *(const uint4*)(wsb + U67_OFF + s6 * 2048 + a7 * 8);

    STAGE_CORE(0, G4);
    STAGE_CORE(1, G5);
    __syncthreads();

    float v[8], acc[8];
    v[0] = va.x; v[1] = va.y; v[2] = va.z; v[3] = va.w;
    v[4] = vb.x; v[5] = vb.y; v[6] = vb.z; v[7] = vb.w;
#pragma unroll
    for (int i = 0; i < 8; ++i) acc[i] = 0.f;

    const uint4* l4 = (const uint4*)lut;
    CHAIN2(s4, s5);

    float q = v[0] * BF2F_LO(ue.x) + v[1] * BF2F_HI(ue.x)
            + v[2] * BF2F_LO(ue.y) + v[3] * BF2F_HI(ue.y)
            + v[4] * BF2F_LO(ue.z) + v[5] * BF2F_HI(ue.z)
            + v[6] * BF2F_LO(ue.w) + v[7] * BF2F_HI(ue.w);
    if (active) out[b] = q;
}

extern "C" void kernel_launch(void* const* d_in, const int* in_sizes, int n_in,
                              void* d_out, int out_size, void* d_ws, size_t ws_size,
                              hipStream_t stream) {
    const float* G0 = (const float*)d_in[0];
    const float* G1 = (const float*)d_in[1];
    const float* G2 = (const float*)d_in[2];
    const float* G3 = (const float*)d_in[3];
    const float* G4 = (const float*)d_in[4];
    const float* G5 = (const float*)d_in[5];
    const float* G6 = (const float*)d_in[6];
    const float* G7 = (const float*)d_in[7];
    const int* states  = (const int*)d_in[8];
    const int* actions = (const int*)d_in[9];
    float* out = (float*)d_out;
    int B = in_sizes[9];

    unsigned short* wsb = (unsigned short*)d_ws;   // 10 MB used
    float* vtmp = (float*)(wsb + VT_OFF);

    const int nblk = (B + 511) / 512;   // 512 for B=262144

    hipLaunchKernelGGL(build_tables, dim3(2 * NN), dim3(256), 0, stream,
                       G0, G1, G6, G7, wsb);
    hipLaunchKernelGGL(tt_lo, dim3(nblk), dim3(512), 0, stream,
                       wsb, G2, G3, states, vtmp, B);
    hipLaunchKernelGGL(tt_hi, dim3(nblk), dim3(512), 0, stream,
                       wsb, G4, G5, states, actions, vtmp, out, B);
}